// Round 1
// baseline (216.014 us; speedup 1.0000x reference)
//
#include <hip/hip_runtime.h>
#include <stdint.h>

typedef unsigned short u16;
typedef unsigned int u32;

#define NROWS 1024
#define DDIM  1024
#define SLEN  64
#define BATCH 64
#define VOCAB 32000
#define NBN   (VOCAB / 128)   // 250 column blocks
#define PAD_WORD 1

typedef __attribute__((ext_vector_type(4))) float f32x4;
typedef __attribute__((ext_vector_type(8))) short s16x8;

__device__ __forceinline__ u16 f2bf(float x) {
  union { float f; u32 u; } v; v.f = x;
  u32 r = v.u + 0x7FFF + ((v.u >> 16) & 1);   // RNE
  return (u16)(r >> 16);
}

// ---------------- kernel 1: p_copy + hidden -> bf16 ----------------
__global__ __launch_bounds__(256) void prep_kernel(
    const float* __restrict__ hidden, const float* __restrict__ w_copy,
    const float* __restrict__ b_copy, u16* __restrict__ hbf,
    float* __restrict__ pcopy)
{
  const int n = blockIdx.x;
  const int tid = threadIdx.x;
  float4 h = ((const float4*)(hidden + (size_t)n * DDIM))[tid];
  float4 w = ((const float4*)w_copy)[tid];
  ushort4 hb;
  hb.x = f2bf(h.x); hb.y = f2bf(h.y); hb.z = f2bf(h.z); hb.w = f2bf(h.w);
  ((ushort4*)(hbf + (size_t)n * DDIM))[tid] = hb;
  float d = h.x * w.x + h.y * w.y + h.z * w.z + h.w * w.w;
  #pragma unroll
  for (int m = 1; m < 64; m <<= 1) d += __shfl_xor(d, m);
  __shared__ float ws4[4];
  if ((tid & 63) == 0) ws4[tid >> 6] = d;
  __syncthreads();
  if (tid == 0) {
    float s = ws4[0] + ws4[1] + ws4[2] + ws4[3] + b_copy[0];
    pcopy[n] = 1.0f / (1.0f + __expf(-s));
  }
}

// ---------------- kernel 2: W -> bf16 ----------------
__global__ __launch_bounds__(256) void convw_kernel(
    const float* __restrict__ W, u16* __restrict__ Wb)
{
  const int total = VOCAB * DDIM / 8;      // 4,096,000 chunks of 8 floats
  const int stride = gridDim.x * blockDim.x;
  for (int i = blockIdx.x * 256 + threadIdx.x; i < total; i += stride) {
    const float4* p = (const float4*)(W + (size_t)i * 8);
    float4 a = p[0], b = p[1];
    uint4 q;
    q.x = (u32)f2bf(a.x) | ((u32)f2bf(a.y) << 16);
    q.y = (u32)f2bf(a.z) | ((u32)f2bf(a.w) << 16);
    q.z = (u32)f2bf(b.x) | ((u32)f2bf(b.y) << 16);
    q.w = (u32)f2bf(b.z) | ((u32)f2bf(b.w) << 16);
    *((uint4*)(Wb + (size_t)i * 8)) = q;
  }
}

// ---------------- kernel 3: bf16 GEMM (B^T layout) + exp epilogue ----------------
// A = hidden_bf16 [1024][1024], B = W_bf16 [32000][1024] (both K-major).
// Writes exp(logit) to out (pad column zeroed), per-(row, colblock) sums to partial.
// LDS XOR swizzle: 16B slot' = slot ^ ((row>>1)&3), applied on BOTH the
// global_load_lds source address and the ds_read address (rule #21).
__global__ __launch_bounds__(256) void gemm_exp_kernel(
    const u16* __restrict__ A, const u16* __restrict__ B,
    float* __restrict__ out, float* __restrict__ partial)
{
  __shared__ u16 lA[128 * 32];
  __shared__ u16 lB[128 * 32];
  __shared__ float rowacc[2][128];

  const int tid  = threadIdx.x;
  const int lane = tid & 63;
  const int wid  = tid >> 6;       // 0..3
  const int wm   = wid >> 1;       // wave row 0..1
  const int wn   = wid & 1;        // wave col 0..1
  const int bid  = blockIdx.x;
  const int bm   = bid & 7;        // 8 row blocks
  const int bn   = bid >> 3;       // 250 col blocks

  const u16* Abase = A + (size_t)(bm * 128) * DDIM;
  const u16* Bbase = B + (size_t)(bn * 128) * DDIM;

  // staging geometry: chunk c = wid*2+i covers LDS bytes [c*1024, c*1024+1024)
  const int srow  = lane >> 2;     // row within chunk (16 rows of 64B)
  const int sslot = lane & 3;      // 16B slot within row

  f32x4 acc[4][4];
  #pragma unroll
  for (int i = 0; i < 4; ++i)
    #pragma unroll
    for (int j = 0; j < 4; ++j)
      acc[i][j] = (f32x4){0.f, 0.f, 0.f, 0.f};

  const int arow  = wm * 64 + (lane & 15);
  const int brow  = wn * 64 + (lane & 15);
  const int kslot = lane >> 4;

  for (int kt = 0; kt < DDIM; kt += 32) {
    #pragma unroll
    for (int i = 0; i < 2; ++i) {
      const int c  = wid * 2 + i;
      const int r  = c * 16 + srow;
      const int gs = sslot ^ ((r >> 1) & 3);
      const u16* gA = Abase + (size_t)r * DDIM + kt + gs * 8;
      const u16* gB = Bbase + (size_t)r * DDIM + kt + gs * 8;
      __builtin_amdgcn_global_load_lds(
          (const __attribute__((address_space(1))) u32*)gA,
          (__attribute__((address_space(3))) u32*)(lA + c * 512 + lane * 8),
          16, 0, 0);
      __builtin_amdgcn_global_load_lds(
          (const __attribute__((address_space(1))) u32*)gB,
          (__attribute__((address_space(3))) u32*)(lB + c * 512 + lane * 8),
          16, 0, 0);
    }
    __syncthreads();

    s16x8 af[4], bf[4];
    #pragma unroll
    for (int mi = 0; mi < 4; ++mi) {
      const int r = arow + mi * 16;
      const int s = kslot ^ ((r >> 1) & 3);
      af[mi] = *(const s16x8*)(lA + r * 32 + s * 8);
    }
    #pragma unroll
    for (int ni = 0; ni < 4; ++ni) {
      const int r = brow + ni * 16;
      const int s = kslot ^ ((r >> 1) & 3);
      bf[ni] = *(const s16x8*)(lB + r * 32 + s * 8);
    }
    #pragma unroll
    for (int mi = 0; mi < 4; ++mi)
      #pragma unroll
      for (int ni = 0; ni < 4; ++ni)
        acc[mi][ni] = __builtin_amdgcn_mfma_f32_16x16x32_bf16(
            af[mi], bf[ni], acc[mi][ni], 0, 0, 0);
    __syncthreads();
  }

  // ---- epilogue: e = exp(logit), write, row-sum ----
  const int g    = lane >> 4;       // C/D: row = g*4 + reg, col = lane&15
  const int ccol = lane & 15;
  float rsum[4][4];
  #pragma unroll
  for (int mi = 0; mi < 4; ++mi)
    #pragma unroll
    for (int j = 0; j < 4; ++j) rsum[mi][j] = 0.f;

  const int rowbase = bm * 128 + wm * 64 + g * 4;
  const int colbase = bn * 128 + wn * 64 + ccol;
  #pragma unroll
  for (int mi = 0; mi < 4; ++mi) {
    #pragma unroll
    for (int j = 0; j < 4; ++j) {
      const size_t row = (size_t)(rowbase + mi * 16 + j);
      float* orow = out + row * VOCAB;
      #pragma unroll
      for (int ni = 0; ni < 4; ++ni) {
        const int col = colbase + ni * 16;
        float e = __expf(acc[mi][ni][j]);
        if (col == PAD_WORD) e = 0.f;
        orow[col] = e;
        rsum[mi][j] += e;
      }
    }
  }
  #pragma unroll
  for (int mi = 0; mi < 4; ++mi)
    #pragma unroll
    for (int j = 0; j < 4; ++j) {
      float v = rsum[mi][j];
      v += __shfl_xor(v, 1);
      v += __shfl_xor(v, 2);
      v += __shfl_xor(v, 4);
      v += __shfl_xor(v, 8);
      rsum[mi][j] = v;
    }
  if (ccol == 0) {
    #pragma unroll
    for (int mi = 0; mi < 4; ++mi)
      #pragma unroll
      for (int j = 0; j < 4; ++j)
        rowacc[wn][wm * 64 + mi * 16 + g * 4 + j] = rsum[mi][j];
  }
  __syncthreads();
  if (tid < 128)
    partial[(size_t)bn * NROWS + bm * 128 + tid] = rowacc[0][tid] + rowacc[1][tid];
}

// ---------------- kernel 4: reduce partials -> scale/ofs ----------------
__global__ __launch_bounds__(256) void rowsum_kernel(
    const float* __restrict__ partial, const float* __restrict__ pcopy,
    float* __restrict__ scale, float* __restrict__ ofs)
{
  const int n = blockIdx.x * 256 + threadIdx.x;
  if (n >= NROWS) return;
  float s = 0.f;
  for (int j = 0; j < NBN; ++j) s += partial[(size_t)j * NROWS + n];
  const float p = pcopy[n];
  scale[n] = (1.0f - p) / s;
  ofs[n]   = (1.0f - p) * 1e-20f;
}

// ---------------- kernel 5: normalize in place ----------------
__global__ __launch_bounds__(256) void norm_kernel(
    float* __restrict__ out, const float* __restrict__ scale,
    const float* __restrict__ ofs)
{
  const int total4 = NROWS * VOCAB / 4;     // 8,192,000
  const int stride = gridDim.x * blockDim.x;
  for (int i = blockIdx.x * 256 + threadIdx.x; i < total4; i += stride) {
    const int n = i / (VOCAB / 4);
    float4* p = (float4*)out + i;
    float4 v = *p;
    const float sc = scale[n], of = ofs[n];
    v.x = v.x * sc + of;
    v.y = v.y * sc + of;
    v.z = v.z * sc + of;
    v.w = v.w * sc + of;
    *p = v;
  }
}

// ---------------- kernel 6: scatter-add copy mass ----------------
__global__ __launch_bounds__(256) void scatter_kernel(
    float* __restrict__ out, const float* __restrict__ attn,
    const int* __restrict__ src, const float* __restrict__ pcopy)
{
  const int t = blockIdx.x * 256 + threadIdx.x;   // 65536 total
  const int n = t >> 6;
  const int s = t & 63;
  const int b = n & (BATCH - 1);
  const int v = src[s * BATCH + b];
  const float w = pcopy[n] * attn[(size_t)n * SLEN + s];
  atomicAdd(out + (size_t)n * VOCAB + v, w);
}

extern "C" void kernel_launch(void* const* d_in, const int* in_sizes, int n_in,
                              void* d_out, int out_size, void* d_ws, size_t ws_size,
                              hipStream_t stream) {
  const float* hidden = (const float*)d_in[0];
  const float* attn   = (const float*)d_in[1];
  const int*   src    = (const int*)d_in[2];
  const float* W      = (const float*)d_in[3];
  const float* w_copy = (const float*)d_in[4];
  const float* b_copy = (const float*)d_in[5];
  float* out = (float*)d_out;

  char* ws = (char*)d_ws;
  u16*   Wb      = (u16*)ws;                                   // 65,536,000 B
  u16*   hbf     = (u16*)(ws + 65536000);                      //  2,097,152 B
  float* pcopy   = (float*)(ws + 65536000 + 2097152);          //      4,096 B
  float* partial = (float*)(ws + 65536000 + 2097152 + 4096);   //  1,024,000 B
  float* scale   = (float*)(ws + 65536000 + 2097152 + 4096 + 1024000);
  float* ofs     = (float*)(ws + 65536000 + 2097152 + 4096 + 1024000 + 4096);

  prep_kernel<<<NROWS, 256, 0, stream>>>(hidden, w_copy, b_copy, hbf, pcopy);
  convw_kernel<<<2048, 256, 0, stream>>>(W, Wb);
  gemm_exp_kernel<<<8 * NBN, 256, 0, stream>>>(hbf, Wb, out, partial);
  rowsum_kernel<<<(NROWS + 255) / 256, 256, 0, stream>>>(partial, pcopy, scale, ofs);
  norm_kernel<<<2048, 256, 0, stream>>>(out, scale, ofs);
  scatter_kernel<<<NROWS * SLEN / 256, 256, 0, stream>>>(out, attn, src, pcopy);
}

// Round 2
// 194.049 us; speedup vs baseline: 1.1132x; 1.1132x over previous
//
#include <hip/hip_runtime.h>
#include <stdint.h>

typedef unsigned short u16;
typedef unsigned int u32;

#define NROWS 1024
#define DDIM  1024
#define SLEN  64
#define BATCH 64
#define VOCAB 32000
#define NBN   (VOCAB / 128)   // 250 column blocks
#define PAD_WORD 1

typedef __attribute__((ext_vector_type(4))) float f32x4;
typedef __attribute__((ext_vector_type(8))) short s16x8;

__device__ __forceinline__ u16 f2bf(float x) {
  union { float f; u32 u; } v; v.f = x;
  u32 r = v.u + 0x7FFF + ((v.u >> 16) & 1);   // RNE
  return (u16)(r >> 16);
}
__device__ __forceinline__ float bf2f(u16 x) {
  union { u32 u; float f; } v; v.u = ((u32)x) << 16;
  return v.f;
}

// ---------------- kernel 1: p_copy + hidden -> bf16 ----------------
__global__ __launch_bounds__(256) void prep_kernel(
    const float* __restrict__ hidden, const float* __restrict__ w_copy,
    const float* __restrict__ b_copy, u16* __restrict__ hbf,
    float* __restrict__ pcopy)
{
  const int n = blockIdx.x;
  const int tid = threadIdx.x;
  float4 h = ((const float4*)(hidden + (size_t)n * DDIM))[tid];
  float4 w = ((const float4*)w_copy)[tid];
  ushort4 hb;
  hb.x = f2bf(h.x); hb.y = f2bf(h.y); hb.z = f2bf(h.z); hb.w = f2bf(h.w);
  ((ushort4*)(hbf + (size_t)n * DDIM))[tid] = hb;
  float d = h.x * w.x + h.y * w.y + h.z * w.z + h.w * w.w;
  #pragma unroll
  for (int m = 1; m < 64; m <<= 1) d += __shfl_xor(d, m);
  __shared__ float ws4[4];
  if ((tid & 63) == 0) ws4[tid >> 6] = d;
  __syncthreads();
  if (tid == 0) {
    float s = ws4[0] + ws4[1] + ws4[2] + ws4[3] + b_copy[0];
    pcopy[n] = 1.0f / (1.0f + __expf(-s));
  }
}

// ---------------- kernel 2: W -> bf16 ----------------
__global__ __launch_bounds__(256) void convw_kernel(
    const float* __restrict__ W, u16* __restrict__ Wb)
{
  const int total = VOCAB * DDIM / 8;      // 4,096,000 chunks of 8 floats
  const int stride = gridDim.x * blockDim.x;
  for (int i = blockIdx.x * 256 + threadIdx.x; i < total; i += stride) {
    const float4* p = (const float4*)(W + (size_t)i * 8);
    float4 a = p[0], b = p[1];
    uint4 q;
    q.x = (u32)f2bf(a.x) | ((u32)f2bf(a.y) << 16);
    q.y = (u32)f2bf(a.z) | ((u32)f2bf(a.w) << 16);
    q.z = (u32)f2bf(b.x) | ((u32)f2bf(b.y) << 16);
    q.w = (u32)f2bf(b.z) | ((u32)f2bf(b.w) << 16);
    *((uint4*)(Wb + (size_t)i * 8)) = q;
  }
}

// ---------------- kernel 3: bf16 GEMM (B^T layout), BK=64, exp epilogue ----------
// A = hidden_bf16 [1024][1024], B = W_bf16 [32000][1024] (both K-major).
// XCD-chunked block swizzle (2000 % 8 == 0 -> bijective).
// LDS tiles 128x64 bf16 (128B rows = exact bank wrap) -> XOR swizzle
// slot' = slot ^ (row & 7) over the 8 16B slots, applied on BOTH the
// global_load_lds source address and the ds_read address (rule #21).
// Epilogue writes exp(logit) (pad col zeroed) as bf16 to ebf (or f32 to out
// when use_bf16 == 0), plus per-(row, colblock) sums to partial.
__global__ __launch_bounds__(256) void gemm_exp_kernel(
    const u16* __restrict__ A, const u16* __restrict__ B,
    float* __restrict__ out, u16* __restrict__ ebf,
    float* __restrict__ partial, const int use_bf16)
{
  __shared__ u16 lA[128 * 64];
  __shared__ u16 lB[128 * 64];
  __shared__ float rowacc[2][128];

  const int tid  = threadIdx.x;
  const int lane = tid & 63;
  const int wid  = tid >> 6;       // 0..3
  const int wm   = wid >> 1;       // wave row 0..1
  const int wn   = wid & 1;        // wave col 0..1

  const int bid0 = blockIdx.x;
  const int swz  = (bid0 & 7) * 250 + (bid0 >> 3);  // XCD-chunked, bijective
  const int bm   = swz & 7;        // 8 row blocks
  const int bn   = swz >> 3;       // 250 col blocks

  const u16* Abase = A + (size_t)(bm * 128) * DDIM;
  const u16* Bbase = B + (size_t)(bn * 128) * DDIM;

  f32x4 acc[4][4];
  #pragma unroll
  for (int i = 0; i < 4; ++i)
    #pragma unroll
    for (int j = 0; j < 4; ++j)
      acc[i][j] = (f32x4){0.f, 0.f, 0.f, 0.f};

  const int arow  = wm * 64 + (lane & 15);
  const int brow  = wn * 64 + (lane & 15);
  const int kslot = lane >> 4;     // 0..3
  // staging geometry: chunk c covers LDS bytes [c*1024, (c+1)*1024)
  const int srow  = lane >> 3;     // 0..7  (row within chunk, 8 rows of 128B)
  const int sslt  = lane & 7;      // 16B slot within row

  for (int kt = 0; kt < DDIM; kt += 64) {
    #pragma unroll
    for (int i = 0; i < 4; ++i) {
      const int c  = i * 4 + wid;          // 0..15
      const int r  = c * 8 + srow;         // 0..127
      const int gs = sslt ^ (r & 7);       // pre-swizzled source slot
      const u16* gA = Abase + (size_t)r * DDIM + kt + gs * 8;
      const u16* gB = Bbase + (size_t)r * DDIM + kt + gs * 8;
      __builtin_amdgcn_global_load_lds(
          (const __attribute__((address_space(1))) u32*)gA,
          (__attribute__((address_space(3))) u32*)(lA + c * 512 + lane * 8),
          16, 0, 0);
      __builtin_amdgcn_global_load_lds(
          (const __attribute__((address_space(1))) u32*)gB,
          (__attribute__((address_space(3))) u32*)(lB + c * 512 + lane * 8),
          16, 0, 0);
    }
    __syncthreads();

    #pragma unroll
    for (int kk = 0; kk < 2; ++kk) {
      s16x8 af[4], bf[4];
      #pragma unroll
      for (int mi = 0; mi < 4; ++mi) {
        const int r = arow + mi * 16;
        const int s = (kk * 4 + kslot) ^ (r & 7);
        af[mi] = *(const s16x8*)(lA + r * 64 + s * 8);
      }
      #pragma unroll
      for (int ni = 0; ni < 4; ++ni) {
        const int r = brow + ni * 16;
        const int s = (kk * 4 + kslot) ^ (r & 7);
        bf[ni] = *(const s16x8*)(lB + r * 64 + s * 8);
      }
      #pragma unroll
      for (int mi = 0; mi < 4; ++mi)
        #pragma unroll
        for (int ni = 0; ni < 4; ++ni)
          acc[mi][ni] = __builtin_amdgcn_mfma_f32_16x16x32_bf16(
              af[mi], bf[ni], acc[mi][ni], 0, 0, 0);
    }
    __syncthreads();
  }

  // ---- epilogue: e = exp(logit), write (bf16 or f32), row-sum ----
  const int g    = lane >> 4;       // C/D: row = g*4 + reg, col = lane&15
  const int ccol = lane & 15;
  float rsum[4][4];
  #pragma unroll
  for (int mi = 0; mi < 4; ++mi)
    #pragma unroll
    for (int j = 0; j < 4; ++j) rsum[mi][j] = 0.f;

  const int rowbase = bm * 128 + wm * 64 + g * 4;
  const int colbase = bn * 128 + wn * 64 + ccol;
  #pragma unroll
  for (int mi = 0; mi < 4; ++mi) {
    #pragma unroll
    for (int j = 0; j < 4; ++j) {
      const size_t row = (size_t)(rowbase + mi * 16 + j);
      #pragma unroll
      for (int ni = 0; ni < 4; ++ni) {
        const int col = colbase + ni * 16;
        float e = __expf(acc[mi][ni][j]);
        if (col == PAD_WORD) e = 0.f;
        rsum[mi][j] += e;
        if (use_bf16) ebf[row * VOCAB + col] = f2bf(e);
        else          out[row * VOCAB + col] = e;
      }
    }
  }
  #pragma unroll
  for (int mi = 0; mi < 4; ++mi)
    #pragma unroll
    for (int j = 0; j < 4; ++j) {
      float v = rsum[mi][j];
      v += __shfl_xor(v, 1);
      v += __shfl_xor(v, 2);
      v += __shfl_xor(v, 4);
      v += __shfl_xor(v, 8);
      rsum[mi][j] = v;
    }
  if (ccol == 0) {
    #pragma unroll
    for (int mi = 0; mi < 4; ++mi)
      #pragma unroll
      for (int j = 0; j < 4; ++j)
        rowacc[wn][wm * 64 + mi * 16 + g * 4 + j] = rsum[mi][j];
  }
  __syncthreads();
  if (tid < 128)
    partial[(size_t)bn * NROWS + bm * 128 + tid] = rowacc[0][tid] + rowacc[1][tid];
}

// ---------------- kernel 4: reduce partials -> scale/ofs ----------------
__global__ __launch_bounds__(256) void rowsum_kernel(
    const float* __restrict__ partial, const float* __restrict__ pcopy,
    float* __restrict__ scale, float* __restrict__ ofs)
{
  const int n = blockIdx.x * 256 + threadIdx.x;
  if (n >= NROWS) return;
  float s = 0.f;
  for (int j = 0; j < NBN; ++j) s += partial[(size_t)j * NROWS + n];
  const float p = pcopy[n];
  scale[n] = (1.0f - p) / s;
  ofs[n]   = (1.0f - p) * 1e-20f;
}

// ---------------- kernel 5a: normalize from bf16 exp -> f32 out ----------------
__global__ __launch_bounds__(256) void norm_bf16_kernel(
    const u16* __restrict__ ebf, float* __restrict__ out,
    const float* __restrict__ scale, const float* __restrict__ ofs)
{
  const int total8 = NROWS * VOCAB / 8;     // 4,096,000 ; VOCAB/8 = 4000
  const int stride = gridDim.x * blockDim.x;
  for (int i = blockIdx.x * 256 + threadIdx.x; i < total8; i += stride) {
    const int n = i / (VOCAB / 8);
    ushort4 v0 = ((const ushort4*)ebf)[i * 2];
    ushort4 v1 = ((const ushort4*)ebf)[i * 2 + 1];
    const float sc = scale[n], of = ofs[n];
    float4 o0, o1;
    o0.x = bf2f(v0.x) * sc + of; o0.y = bf2f(v0.y) * sc + of;
    o0.z = bf2f(v0.z) * sc + of; o0.w = bf2f(v0.w) * sc + of;
    o1.x = bf2f(v1.x) * sc + of; o1.y = bf2f(v1.y) * sc + of;
    o1.z = bf2f(v1.z) * sc + of; o1.w = bf2f(v1.w) * sc + of;
    ((float4*)out)[i * 2]     = o0;
    ((float4*)out)[i * 2 + 1] = o1;
  }
}

// ---------------- kernel 5b: normalize f32 in place (fallback) ----------------
__global__ __launch_bounds__(256) void norm_kernel(
    float* __restrict__ out, const float* __restrict__ scale,
    const float* __restrict__ ofs)
{
  const int total4 = NROWS * VOCAB / 4;     // 8,192,000
  const int stride = gridDim.x * blockDim.x;
  for (int i = blockIdx.x * 256 + threadIdx.x; i < total4; i += stride) {
    const int n = i / (VOCAB / 4);
    float4* p = (float4*)out + i;
    float4 v = *p;
    const float sc = scale[n], of = ofs[n];
    v.x = v.x * sc + of;
    v.y = v.y * sc + of;
    v.z = v.z * sc + of;
    v.w = v.w * sc + of;
    *p = v;
  }
}

// ---------------- kernel 6: scatter-add copy mass ----------------
__global__ __launch_bounds__(256) void scatter_kernel(
    float* __restrict__ out, const float* __restrict__ attn,
    const int* __restrict__ src, const float* __restrict__ pcopy)
{
  const int t = blockIdx.x * 256 + threadIdx.x;   // 65536 total
  const int n = t >> 6;
  const int s = t & 63;
  const int b = n & (BATCH - 1);
  const int v = src[s * BATCH + b];
  const float w = pcopy[n] * attn[(size_t)n * SLEN + s];
  atomicAdd(out + (size_t)n * VOCAB + v, w);
}

extern "C" void kernel_launch(void* const* d_in, const int* in_sizes, int n_in,
                              void* d_out, int out_size, void* d_ws, size_t ws_size,
                              hipStream_t stream) {
  const float* hidden = (const float*)d_in[0];
  const float* attn   = (const float*)d_in[1];
  const int*   src    = (const int*)d_in[2];
  const float* W      = (const float*)d_in[3];
  const float* w_copy = (const float*)d_in[4];
  const float* b_copy = (const float*)d_in[5];
  float* out = (float*)d_out;

  char* ws = (char*)d_ws;
  u16*   Wb      = (u16*)ws;                                    // 65,536,000 B
  u16*   hbf     = (u16*)(ws + 65536000);                       //  2,097,152 B
  float* pcopy   = (float*)(ws + 67633152);                     //      4,096 B
  float* partial = (float*)(ws + 67637248);                     //  1,024,000 B
  float* scale   = (float*)(ws + 68661248);                     //      4,096 B
  float* ofs     = (float*)(ws + 68665344);                     //      4,096 B
  u16*   ebf     = (u16*)(ws + 68669440);                       // 65,536,000 B
  const size_t need_bf16 = 68669440ull + 65536000ull;
  const int use_bf16 = (ws_size >= need_bf16) ? 1 : 0;

  prep_kernel<<<NROWS, 256, 0, stream>>>(hidden, w_copy, b_copy, hbf, pcopy);
  convw_kernel<<<2048, 256, 0, stream>>>(W, Wb);
  gemm_exp_kernel<<<8 * NBN, 256, 0, stream>>>(hbf, Wb, out, ebf, partial, use_bf16);
  rowsum_kernel<<<(NROWS + 255) / 256, 256, 0, stream>>>(partial, pcopy, scale, ofs);
  if (use_bf16)
    norm_bf16_kernel<<<2048, 256, 0, stream>>>(ebf, out, scale, ofs);
  else
    norm_kernel<<<2048, 256, 0, stream>>>(out, scale, ofs);
  scatter_kernel<<<NROWS * SLEN / 256, 256, 0, stream>>>(out, attn, src, pcopy);
}

// Round 3
// 173.846 us; speedup vs baseline: 1.2426x; 1.1162x over previous
//
#include <hip/hip_runtime.h>
#include <stdint.h>

typedef unsigned short u16;
typedef unsigned int u32;

#define NROWS 1024
#define DDIM  1024
#define SLEN  64
#define BATCH 64
#define VOCAB 32000
#define NBN2  125            // 256-wide column blocks
#define PAD_WORD 1

typedef __attribute__((ext_vector_type(4))) float f32x4;
typedef __attribute__((ext_vector_type(8))) short s16x8;

__device__ __forceinline__ u16 f2bf(float x) {
  union { float f; u32 u; } v; v.f = x;
  u32 r = v.u + 0x7FFF + ((v.u >> 16) & 1);   // RNE
  return (u16)(r >> 16);
}
__device__ __forceinline__ float bf2f(u16 x) {
  union { u32 u; float f; } v; v.u = ((u32)x) << 16;
  return v.f;
}

// ---------------- kernel 1: p_copy + hidden -> bf16 ----------------
__global__ __launch_bounds__(256) void prep_kernel(
    const float* __restrict__ hidden, const float* __restrict__ w_copy,
    const float* __restrict__ b_copy, u16* __restrict__ hbf,
    float* __restrict__ pcopy)
{
  const int n = blockIdx.x;
  const int tid = threadIdx.x;
  float4 h = ((const float4*)(hidden + (size_t)n * DDIM))[tid];
  float4 w = ((const float4*)w_copy)[tid];
  ushort4 hb;
  hb.x = f2bf(h.x); hb.y = f2bf(h.y); hb.z = f2bf(h.z); hb.w = f2bf(h.w);
  ((ushort4*)(hbf + (size_t)n * DDIM))[tid] = hb;
  float d = h.x * w.x + h.y * w.y + h.z * w.z + h.w * w.w;
  #pragma unroll
  for (int m = 1; m < 64; m <<= 1) d += __shfl_xor(d, m);
  __shared__ float ws4[4];
  if ((tid & 63) == 0) ws4[tid >> 6] = d;
  __syncthreads();
  if (tid == 0) {
    float s = ws4[0] + ws4[1] + ws4[2] + ws4[3] + b_copy[0];
    pcopy[n] = 1.0f / (1.0f + __expf(-s));
  }
}

// ---------------- kernel 2: W -> bf16 ----------------
__global__ __launch_bounds__(256) void convw_kernel(
    const float* __restrict__ W, u16* __restrict__ Wb)
{
  const int total = VOCAB * DDIM / 8;      // 4,096,000 chunks of 8 floats
  const int stride = gridDim.x * blockDim.x;
  for (int i = blockIdx.x * 256 + threadIdx.x; i < total; i += stride) {
    const float4* p = (const float4*)(W + (size_t)i * 8);
    float4 a = p[0], b = p[1];
    uint4 q;
    q.x = (u32)f2bf(a.x) | ((u32)f2bf(a.y) << 16);
    q.y = (u32)f2bf(a.z) | ((u32)f2bf(a.w) << 16);
    q.z = (u32)f2bf(b.x) | ((u32)f2bf(b.y) << 16);
    q.w = (u32)f2bf(b.z) | ((u32)f2bf(b.w) << 16);
    *((uint4*)(Wb + (size_t)i * 8)) = q;
  }
}

// -------- kernel 3: 256x256 8-phase bf16 GEMM (B^T), BK=64, exp epilogue -------
// A = hidden_bf16 [1024][1024], B = W_bf16 [32000][1024] (K-major).
// 8 waves as 2(M)x4(N); per-wave C = 128x64. Double-buffered LDS, 4 half-tiles
// per K-tile (A0,A1,B0,B1 of 128x64 each). XOR swizzle slot' = slot ^ (row&7)
// applied on both the gload_lds source address and the ds_read address.
// Stage stream: ph0->A1(t+1), ph1->B0(t+1), ph2->B1(t+1) into idle buffer;
// ph3->A0(t+2) into current buffer (fully consumed after ph2's barrier).
// vmcnt(2) once per K-tile at ph3 (never 0).
__global__ __launch_bounds__(512, 2) void gemm_exp_kernel(
    const u16* __restrict__ A, const u16* __restrict__ B,
    float* __restrict__ out, u16* __restrict__ ebf,
    float* __restrict__ partial, const int use_bf16)
{
  __shared__ u16 lA[2][16384];     // [dbuf][half(8192) | row(64) | slot]
  __shared__ u16 lB[2][16384];
  __shared__ float rowacc[4][256];

  const int tid  = threadIdx.x;
  const int lane = tid & 63;
  const int wid  = tid >> 6;        // 0..7
  const int wm   = wid >> 2;        // 0..1  (M)
  const int wn   = wid & 3;         // 0..3  (N)
  const int al   = lane & 15;
  const int ks   = lane >> 4;       // 0..3

  // bijective XCD-chunked swizzle for 500 blocks (q=62, r=4)
  const int orig = blockIdx.x;
  const int xcd  = orig & 7;
  const int idx  = orig >> 3;
  const int wg   = (xcd < 4 ? xcd * 63 : 252 + (xcd - 4) * 62) + idx;
  const int bm   = wg & 3;          // 4 M-blocks
  const int bn   = wg >> 2;         // 125 N-blocks

  const u16* Abase = A + (size_t)(bm * 256) * DDIM;
  const u16* Bbase = B + (size_t)(bn * 256) * DDIM;

  // staging geometry: thread covers linear slots s0 and s0+64 of a half-tile
  const int s0  = wid * 128 + lane;      // 0..1023 (slot = 16B)
  const int rr0 = s0 >> 3;               // row within half (0..127)
  const int cs0 = (s0 & 7) ^ (rr0 & 7);  // pre-swizzled source slot
  // l=1: row rr0+8, same cs0 (since (rr0+8)&7 == rr0&7), lds +1024B

#define STAGE(gptr, lptr) do { \
    __builtin_amdgcn_global_load_lds( \
        (const __attribute__((address_space(1))) u32*)((gptr) + (size_t)rr0 * DDIM + cs0 * 8), \
        (__attribute__((address_space(3))) u32*)((lptr) + s0 * 8), 16, 0, 0); \
    __builtin_amdgcn_global_load_lds( \
        (const __attribute__((address_space(1))) u32*)((gptr) + (size_t)(rr0 + 8) * DDIM + cs0 * 8), \
        (__attribute__((address_space(3))) u32*)((lptr) + s0 * 8 + 512), 16, 0, 0); \
  } while (0)

  // ---- prologue: tile0 (4 halves) + A0 of tile1 ----
  STAGE(Abase,                 &lA[0][0]);
  STAGE(Abase + 128 * DDIM,    &lA[0][8192]);
  STAGE(Bbase,                 &lB[0][0]);
  STAGE(Bbase + 128 * DDIM,    &lB[0][8192]);
  STAGE(Abase + 64,            &lA[1][0]);
  asm volatile("s_waitcnt vmcnt(2)");
  __builtin_amdgcn_s_barrier();
  __builtin_amdgcn_sched_barrier(0);

  f32x4 acc[8][4];
  #pragma unroll
  for (int i = 0; i < 8; ++i)
    #pragma unroll
    for (int j = 0; j < 4; ++j)
      acc[i][j] = (f32x4){0.f, 0.f, 0.f, 0.f};

  s16x8 afr[4][2], b0r[2][2], b1r[2][2];

  #pragma unroll 2
  for (int t = 0; t < 16; ++t) {
    const int cur = t & 1;
    u16* lAc = &lA[cur][0];
    u16* lBc = &lB[cur][0];
    u16* lAn = &lA[cur ^ 1][0];
    u16* lBn = &lB[cur ^ 1][0];
    const int kt1 = ((t + 1) & 15) * 64;
    const int kt2 = ((t + 2) & 15) * 64;

    // ---- phase 0: read A[mh=0] + B[nh=0]; stage A1(t+1); MFMA (0,0) ----
    #pragma unroll
    for (int mi = 0; mi < 4; ++mi) {
      const int rih = mi * 16 + al;
      #pragma unroll
      for (int kk = 0; kk < 2; ++kk) {
        const int sl = (kk * 4 + ks) ^ (rih & 7);
        afr[mi][kk] = *(const s16x8*)(lAc + wm * 8192 + rih * 64 + sl * 8);
      }
    }
    #pragma unroll
    for (int ni = 0; ni < 2; ++ni) {
      const int rih = (wn & 1) * 64 + ni * 16 + al;
      #pragma unroll
      for (int kk = 0; kk < 2; ++kk) {
        const int sl = (kk * 4 + ks) ^ (rih & 7);
        b0r[ni][kk] = *(const s16x8*)(lBc + (wn >> 1) * 8192 + rih * 64 + sl * 8);
      }
    }
    STAGE(Abase + 128 * DDIM + kt1, lAn + 8192);
    __builtin_amdgcn_s_barrier();
    asm volatile("s_waitcnt lgkmcnt(0)");
    __builtin_amdgcn_sched_barrier(0);
    __builtin_amdgcn_s_setprio(1);
    #pragma unroll
    for (int mi = 0; mi < 4; ++mi)
      #pragma unroll
      for (int ni = 0; ni < 2; ++ni)
        #pragma unroll
        for (int kk = 0; kk < 2; ++kk)
          acc[mi][ni] = __builtin_amdgcn_mfma_f32_16x16x32_bf16(
              afr[mi][kk], b0r[ni][kk], acc[mi][ni], 0, 0, 0);
    __builtin_amdgcn_s_setprio(0);
    __builtin_amdgcn_s_barrier();
    __builtin_amdgcn_sched_barrier(0);

    // ---- phase 1: read B[nh=1]; stage B0(t+1); MFMA (0,1) ----
    #pragma unroll
    for (int ni = 0; ni < 2; ++ni) {
      const int rih = (wn & 1) * 64 + 32 + ni * 16 + al;
      #pragma unroll
      for (int kk = 0; kk < 2; ++kk) {
        const int sl = (kk * 4 + ks) ^ (rih & 7);
        b1r[ni][kk] = *(const s16x8*)(lBc + (wn >> 1) * 8192 + rih * 64 + sl * 8);
      }
    }
    STAGE(Bbase + kt1, lBn);
    __builtin_amdgcn_s_barrier();
    asm volatile("s_waitcnt lgkmcnt(0)");
    __builtin_amdgcn_sched_barrier(0);
    __builtin_amdgcn_s_setprio(1);
    #pragma unroll
    for (int mi = 0; mi < 4; ++mi)
      #pragma unroll
      for (int ni = 0; ni < 2; ++ni)
        #pragma unroll
        for (int kk = 0; kk < 2; ++kk)
          acc[mi][2 + ni] = __builtin_amdgcn_mfma_f32_16x16x32_bf16(
              afr[mi][kk], b1r[ni][kk], acc[mi][2 + ni], 0, 0, 0);
    __builtin_amdgcn_s_setprio(0);
    __builtin_amdgcn_s_barrier();
    __builtin_amdgcn_sched_barrier(0);

    // ---- phase 2: read A[mh=1]; stage B1(t+1); MFMA (1,0) ----
    #pragma unroll
    for (int mi = 0; mi < 4; ++mi) {
      const int rih = 64 + mi * 16 + al;
      #pragma unroll
      for (int kk = 0; kk < 2; ++kk) {
        const int sl = (kk * 4 + ks) ^ (rih & 7);
        afr[mi][kk] = *(const s16x8*)(lAc + wm * 8192 + rih * 64 + sl * 8);
      }
    }
    STAGE(Bbase + 128 * DDIM + kt1, lBn + 8192);
    __builtin_amdgcn_s_barrier();
    asm volatile("s_waitcnt lgkmcnt(0)");
    __builtin_amdgcn_sched_barrier(0);
    __builtin_amdgcn_s_setprio(1);
    #pragma unroll
    for (int mi = 0; mi < 4; ++mi)
      #pragma unroll
      for (int ni = 0; ni < 2; ++ni)
        #pragma unroll
        for (int kk = 0; kk < 2; ++kk)
          acc[4 + mi][ni] = __builtin_amdgcn_mfma_f32_16x16x32_bf16(
              afr[mi][kk], b0r[ni][kk], acc[4 + mi][ni], 0, 0, 0);
    __builtin_amdgcn_s_setprio(0);
    __builtin_amdgcn_s_barrier();
    __builtin_amdgcn_sched_barrier(0);

    // ---- phase 3: stage A0(t+2) into current buffer; MFMA (1,1); vmcnt(2) ----
    STAGE(Abase + kt2, lAc);
    __builtin_amdgcn_s_barrier();
    __builtin_amdgcn_s_setprio(1);
    #pragma unroll
    for (int mi = 0; mi < 4; ++mi)
      #pragma unroll
      for (int ni = 0; ni < 2; ++ni)
        #pragma unroll
        for (int kk = 0; kk < 2; ++kk)
          acc[4 + mi][2 + ni] = __builtin_amdgcn_mfma_f32_16x16x32_bf16(
              afr[mi][kk], b1r[ni][kk], acc[4 + mi][2 + ni], 0, 0, 0);
    __builtin_amdgcn_s_setprio(0);
    asm volatile("s_waitcnt vmcnt(2)");
    __builtin_amdgcn_s_barrier();
    __builtin_amdgcn_sched_barrier(0);
  }
#undef STAGE

  // ---- epilogue: e = exp(logit), write (bf16 or f32), row-sums ----
  const int g = ks;                 // C/D: row = g*4 + j, col = lane&15
  float rsum[8][4];
  #pragma unroll
  for (int mi = 0; mi < 8; ++mi)
    #pragma unroll
    for (int j = 0; j < 4; ++j) rsum[mi][j] = 0.f;

  const size_t grow0 = (size_t)(bm * 256 + wm * 128);
  const int gcol0 = bn * 256 + wn * 64;
  #pragma unroll
  for (int mi = 0; mi < 8; ++mi) {
    const int rofs = (mi >> 2) * 64 + (mi & 3) * 16 + g * 4;
    #pragma unroll
    for (int j = 0; j < 4; ++j) {
      const size_t row = grow0 + rofs + j;
      #pragma unroll
      for (int ni = 0; ni < 4; ++ni) {
        const int col = gcol0 + (ni >> 1) * 32 + (ni & 1) * 16 + al;
        float e = __expf(acc[mi][ni][j]);
        if (col == PAD_WORD) e = 0.f;
        rsum[mi][j] += e;
        if (use_bf16) ebf[row * VOCAB + col] = f2bf(e);
        else          out[row * VOCAB + col] = e;
      }
    }
  }
  #pragma unroll
  for (int mi = 0; mi < 8; ++mi)
    #pragma unroll
    for (int j = 0; j < 4; ++j) {
      float v = rsum[mi][j];
      v += __shfl_xor(v, 1);
      v += __shfl_xor(v, 2);
      v += __shfl_xor(v, 4);
      v += __shfl_xor(v, 8);
      rsum[mi][j] = v;
    }
  if (al == 0) {
    #pragma unroll
    for (int mi = 0; mi < 8; ++mi)
      #pragma unroll
      for (int j = 0; j < 4; ++j)
        rowacc[wn][wm * 128 + (mi >> 2) * 64 + (mi & 3) * 16 + g * 4 + j] =
            rsum[mi][j];
  }
  __syncthreads();
  if (tid < 256)
    partial[(size_t)bn * NROWS + bm * 256 + tid] =
        rowacc[0][tid] + rowacc[1][tid] + rowacc[2][tid] + rowacc[3][tid];
}

// ---------------- kernel 4: reduce partials -> scale/ofs ----------------
__global__ __launch_bounds__(256) void rowsum_kernel(
    const float* __restrict__ partial, const float* __restrict__ pcopy,
    float* __restrict__ scale, float* __restrict__ ofs)
{
  const int n = blockIdx.x * 256 + threadIdx.x;
  if (n >= NROWS) return;
  float s = 0.f;
  for (int j = 0; j < NBN2; ++j) s += partial[(size_t)j * NROWS + n];
  const float p = pcopy[n];
  scale[n] = (1.0f - p) / s;
  ofs[n]   = (1.0f - p) * 1e-20f;
}

// ---------------- kernel 5a: normalize from bf16 exp -> f32 out ----------------
__global__ __launch_bounds__(256) void norm_bf16_kernel(
    const u16* __restrict__ ebf, float* __restrict__ out,
    const float* __restrict__ scale, const float* __restrict__ ofs)
{
  const int total8 = NROWS * VOCAB / 8;     // 4,096,000 ; VOCAB/8 = 4000
  const int stride = gridDim.x * blockDim.x;
  for (int i = blockIdx.x * 256 + threadIdx.x; i < total8; i += stride) {
    const int n = i / (VOCAB / 8);
    ushort4 v0 = ((const ushort4*)ebf)[i * 2];
    ushort4 v1 = ((const ushort4*)ebf)[i * 2 + 1];
    const float sc = scale[n], of = ofs[n];
    float4 o0, o1;
    o0.x = bf2f(v0.x) * sc + of; o0.y = bf2f(v0.y) * sc + of;
    o0.z = bf2f(v0.z) * sc + of; o0.w = bf2f(v0.w) * sc + of;
    o1.x = bf2f(v1.x) * sc + of; o1.y = bf2f(v1.y) * sc + of;
    o1.z = bf2f(v1.z) * sc + of; o1.w = bf2f(v1.w) * sc + of;
    ((float4*)out)[i * 2]     = o0;
    ((float4*)out)[i * 2 + 1] = o1;
  }
}

// ---------------- kernel 5b: normalize f32 in place (fallback) ----------------
__global__ __launch_bounds__(256) void norm_kernel(
    float* __restrict__ out, const float* __restrict__ scale,
    const float* __restrict__ ofs)
{
  const int total4 = NROWS * VOCAB / 4;     // 8,192,000
  const int stride = gridDim.x * blockDim.x;
  for (int i = blockIdx.x * 256 + threadIdx.x; i < total4; i += stride) {
    const int n = i / (VOCAB / 4);
    float4* p = (float4*)out + i;
    float4 v = *p;
    const float sc = scale[n], of = ofs[n];
    v.x = v.x * sc + of;
    v.y = v.y * sc + of;
    v.z = v.z * sc + of;
    v.w = v.w * sc + of;
    *p = v;
  }
}

// ---------------- kernel 6: scatter-add copy mass ----------------
__global__ __launch_bounds__(256) void scatter_kernel(
    float* __restrict__ out, const float* __restrict__ attn,
    const int* __restrict__ src, const float* __restrict__ pcopy)
{
  const int t = blockIdx.x * 256 + threadIdx.x;   // 65536 total
  const int n = t >> 6;
  const int s = t & 63;
  const int b = n & (BATCH - 1);
  const int v = src[s * BATCH + b];
  const float w = pcopy[n] * attn[(size_t)n * SLEN + s];
  atomicAdd(out + (size_t)n * VOCAB + v, w);
}

extern "C" void kernel_launch(void* const* d_in, const int* in_sizes, int n_in,
                              void* d_out, int out_size, void* d_ws, size_t ws_size,
                              hipStream_t stream) {
  const float* hidden = (const float*)d_in[0];
  const float* attn   = (const float*)d_in[1];
  const int*   src    = (const int*)d_in[2];
  const float* W      = (const float*)d_in[3];
  const float* w_copy = (const float*)d_in[4];
  const float* b_copy = (const float*)d_in[5];
  float* out = (float*)d_out;

  char* ws = (char*)d_ws;
  u16*   Wb      = (u16*)ws;                                    // 65,536,000 B
  u16*   hbf     = (u16*)(ws + 65536000);                       //  2,097,152 B
  float* pcopy   = (float*)(ws + 67633152);                     //      4,096 B
  float* partial = (float*)(ws + 67637248);                     //  1,024,000 B
  float* scale   = (float*)(ws + 68661248);                     //      4,096 B
  float* ofs     = (float*)(ws + 68665344);                     //      4,096 B
  u16*   ebf     = (u16*)(ws + 68669440);                       // 65,536,000 B
  const size_t need_bf16 = 68669440ull + 65536000ull;
  const int use_bf16 = (ws_size >= need_bf16) ? 1 : 0;

  prep_kernel<<<NROWS, 256, 0, stream>>>(hidden, w_copy, b_copy, hbf, pcopy);
  convw_kernel<<<2048, 256, 0, stream>>>(W, Wb);
  gemm_exp_kernel<<<4 * NBN2, 512, 0, stream>>>(hbf, Wb, out, ebf, partial, use_bf16);
  rowsum_kernel<<<(NROWS + 255) / 256, 256, 0, stream>>>(partial, pcopy, scale, ofs);
  if (use_bf16)
    norm_bf16_kernel<<<2048, 256, 0, stream>>>(ebf, out, scale, ofs);
  else
    norm_kernel<<<2048, 256, 0, stream>>>(out, scale, ofs);
  scatter_kernel<<<NROWS * SLEN / 256, 256, 0, stream>>>(out, attn, src, pcopy);
}

// Round 4
// 165.030 us; speedup vs baseline: 1.3089x; 1.0534x over previous
//
#include <hip/hip_runtime.h>
#include <stdint.h>

typedef unsigned short u16;
typedef unsigned int u32;

#define NROWS 1024
#define DDIM  1024
#define SLEN  64
#define BATCH 64
#define VOCAB 32000
#define NBN2  125            // 256-wide column blocks
#define PAD_WORD 1

typedef __attribute__((ext_vector_type(4))) float f32x4;
typedef __attribute__((ext_vector_type(8))) short s16x8;

__device__ __forceinline__ u16 f2bf(float x) {
  union { float f; u32 u; } v; v.f = x;
  u32 r = v.u + 0x7FFF + ((v.u >> 16) & 1);   // RNE
  return (u16)(r >> 16);
}
__device__ __forceinline__ float bf2f(u16 x) {
  union { u32 u; float f; } v; v.u = ((u32)x) << 16;
  return v.f;
}

// ------------- kernel 1: fused {p_copy + hidden->bf16} and {W->bf16} -------------
__global__ __launch_bounds__(256) void prep_convw_kernel(
    const float* __restrict__ hidden, const float* __restrict__ w_copy,
    const float* __restrict__ b_copy, u16* __restrict__ hbf,
    float* __restrict__ pcopy, const float* __restrict__ W,
    u16* __restrict__ Wb)
{
  const int tid = threadIdx.x;
  if (blockIdx.x < NROWS) {
    // ---- prep: one row per block ----
    const int n = blockIdx.x;
    float4 h = ((const float4*)(hidden + (size_t)n * DDIM))[tid];
    float4 w = ((const float4*)w_copy)[tid];
    ushort4 hb;
    hb.x = f2bf(h.x); hb.y = f2bf(h.y); hb.z = f2bf(h.z); hb.w = f2bf(h.w);
    ((ushort4*)(hbf + (size_t)n * DDIM))[tid] = hb;
    float d = h.x * w.x + h.y * w.y + h.z * w.z + h.w * w.w;
    #pragma unroll
    for (int m = 1; m < 64; m <<= 1) d += __shfl_xor(d, m);
    __shared__ float ws4[4];
    if ((tid & 63) == 0) ws4[tid >> 6] = d;
    __syncthreads();
    if (tid == 0) {
      float s = ws4[0] + ws4[1] + ws4[2] + ws4[3] + b_copy[0];
      pcopy[n] = 1.0f / (1.0f + __expf(-s));
    }
    return;
  }
  // ---- convw: grid-stride over remaining blocks ----
  const int total = VOCAB * DDIM / 8;
  const int stride = (gridDim.x - NROWS) * 256;
  for (int i = (blockIdx.x - NROWS) * 256 + tid; i < total; i += stride) {
    const float4* p = (const float4*)(W + (size_t)i * 8);
    float4 a = p[0], b = p[1];
    uint4 q;
    q.x = (u32)f2bf(a.x) | ((u32)f2bf(a.y) << 16);
    q.y = (u32)f2bf(a.z) | ((u32)f2bf(a.w) << 16);
    q.z = (u32)f2bf(b.x) | ((u32)f2bf(b.y) << 16);
    q.w = (u32)f2bf(b.z) | ((u32)f2bf(b.w) << 16);
    *((uint4*)(Wb + (size_t)i * 8)) = q;
  }
}

// -------- kernel 2: 256x256 bf16 GEMM (B^T), BK=64, interleaved 2-barrier K-loop,
//          exp epilogue. Counted lgkmcnt pipelines fragment reads under MFMA. --------
__global__ __launch_bounds__(512, 2) void gemm_exp_kernel(
    const u16* __restrict__ A, const u16* __restrict__ B,
    float* __restrict__ out, u16* __restrict__ ebf,
    float* __restrict__ partial, const int use_bf16)
{
  __shared__ u16 lA[2][16384];     // [dbuf][lo-half(8192) | hi-half]
  __shared__ u16 lB[2][16384];
  __shared__ float rowacc[4][256];

  const int tid  = threadIdx.x;
  const int lane = tid & 63;
  const int wid  = tid >> 6;        // 0..7
  const int wm   = wid >> 2;        // 0..1  (M)
  const int wn   = wid & 3;         // 0..3  (N)
  const int al   = lane & 15;
  const int ks   = lane >> 4;       // 0..3

  // bijective XCD-chunked swizzle for 500 blocks (q=62, r=4)
  const int orig = blockIdx.x;
  const int xcd  = orig & 7;
  const int idx  = orig >> 3;
  const int wg   = (xcd < 4 ? xcd * 63 : 252 + (xcd - 4) * 62) + idx;
  const int bm   = wg & 3;          // 4 M-blocks
  const int bn   = wg >> 2;         // 125 N-blocks

  const u16* Abase = A + (size_t)(bm * 256) * DDIM;
  const u16* Bbase = B + (size_t)(bn * 256) * DDIM;

  const int s0  = wid * 128 + lane;      // 0..1023 (16B slots of a half-tile)
  const int rr0 = s0 >> 3;               // row within half (0..127)
  const int cs0 = (s0 & 7) ^ (rr0 & 7);  // pre-swizzled source slot

#define STAGE(gptr, lptr) do { \
    __builtin_amdgcn_global_load_lds( \
        (const __attribute__((address_space(1))) u32*)((gptr) + (size_t)rr0 * DDIM + cs0 * 8), \
        (__attribute__((address_space(3))) u32*)((lptr) + s0 * 8), 16, 0, 0); \
    __builtin_amdgcn_global_load_lds( \
        (const __attribute__((address_space(1))) u32*)((gptr) + (size_t)(rr0 + 8) * DDIM + cs0 * 8), \
        (__attribute__((address_space(3))) u32*)((lptr) + s0 * 8 + 512), 16, 0, 0); \
  } while (0)

#define WL(n) do { asm volatile("s_waitcnt lgkmcnt(" #n ")" ::: "memory"); \
                   __builtin_amdgcn_sched_barrier(0); } while (0)
#define WV(n) do { asm volatile("s_waitcnt vmcnt(" #n ")" ::: "memory"); \
                   __builtin_amdgcn_sched_barrier(0); } while (0)
#define BAR() do { __builtin_amdgcn_sched_barrier(0); \
                   __builtin_amdgcn_s_barrier(); \
                   __builtin_amdgcn_sched_barrier(0); } while (0)

#define RD_ALO(buf) do { \
    _Pragma("unroll") \
    for (int mi = 0; mi < 4; ++mi) { \
      const u16* p_ = (buf) + wm * 8192 + (mi * 16 + al) * 64; \
      alo[mi][0] = *(const s16x8*)(p_ + (ks ^ (al & 7)) * 8); \
      alo[mi][1] = *(const s16x8*)(p_ + ((4 + ks) ^ (al & 7)) * 8); \
    } } while (0)
#define RD_AHI(buf) do { \
    _Pragma("unroll") \
    for (int mi = 0; mi < 4; ++mi) { \
      const u16* p_ = (buf) + wm * 8192 + (64 + mi * 16 + al) * 64; \
      ahi[mi][0] = *(const s16x8*)(p_ + (ks ^ (al & 7)) * 8); \
      ahi[mi][1] = *(const s16x8*)(p_ + ((4 + ks) ^ (al & 7)) * 8); \
    } } while (0)
#define RD_B0(buf) do { \
    _Pragma("unroll") \
    for (int ni = 0; ni < 2; ++ni) { \
      const u16* p_ = (buf) + (wn >> 1) * 8192 + ((wn & 1) * 64 + ni * 16 + al) * 64; \
      b0f[ni][0] = *(const s16x8*)(p_ + (ks ^ (al & 7)) * 8); \
      b0f[ni][1] = *(const s16x8*)(p_ + ((4 + ks) ^ (al & 7)) * 8); \
    } } while (0)
#define RD_B1(buf) do { \
    _Pragma("unroll") \
    for (int ni = 0; ni < 2; ++ni) { \
      const u16* p_ = (buf) + (wn >> 1) * 8192 + ((wn & 1) * 64 + 32 + ni * 16 + al) * 64; \
      b1f[ni][0] = *(const s16x8*)(p_ + (ks ^ (al & 7)) * 8); \
      b1f[ni][1] = *(const s16x8*)(p_ + ((4 + ks) ^ (al & 7)) * 8); \
    } } while (0)
#define MM(AF, BF, r0, c0) do { \
    __builtin_amdgcn_s_setprio(1); \
    _Pragma("unroll") \
    for (int mi = 0; mi < 4; ++mi) \
      _Pragma("unroll") \
      for (int ni = 0; ni < 2; ++ni) \
        _Pragma("unroll") \
        for (int kk = 0; kk < 2; ++kk) \
          acc[(r0) + mi][(c0) + ni] = __builtin_amdgcn_mfma_f32_16x16x32_bf16( \
              AF[mi][kk], BF[ni][kk], acc[(r0) + mi][(c0) + ni], 0, 0, 0); \
    __builtin_amdgcn_s_setprio(0); \
  } while (0)

  u16* lAc = &lA[0][0]; u16* lBc = &lB[0][0];
  u16* lAn = &lA[1][0]; u16* lBn = &lB[1][0];

  // ---- prologue: tile0 (4 halves) + Alo(1) ----
  STAGE(Abase,              lAc);
  STAGE(Abase + 128 * DDIM, lAc + 8192);
  STAGE(Bbase,              lBc);
  STAGE(Bbase + 128 * DDIM, lBc + 8192);
  STAGE(Abase + 64,         lAn);
  WV(2);
  BAR();

  f32x4 acc[8][4];
  #pragma unroll
  for (int i = 0; i < 8; ++i)
    #pragma unroll
    for (int j = 0; j < 4; ++j)
      acc[i][j] = (f32x4){0.f, 0.f, 0.f, 0.f};

  s16x8 alo[4][2], ahi[4][2], b0f[2][2], b1f[2][2];

  RD_ALO(lAc); RD_B0(lBc); RD_B1(lBc);
  STAGE(Abase + 128 * DDIM + 64, lAn + 8192);    // Ahi(1)

  for (int t = 0; t < 15; ++t) {
    const int kt1 = (t + 1) * 64;
    const int kt2 = (t + 2) * 64;                // only used when t < 14
    WL(4);                                       // Alo,B0 ready (B1 may fly)
    MM(alo, b0f, 0, 0);
    STAGE(Bbase + kt1, lBn);                     // B0(t+1)
    RD_AHI(lAc);
    WL(8);                                       // B1 ready (Ahi flying)
    MM(alo, b1f, 0, 2);
    STAGE(Bbase + 128 * DDIM + kt1, lBn + 8192); // B1(t+1)
    WL(0);                                       // Ahi ready
    MM(ahi, b0f, 4, 0);
    BAR();                                       // all reads of buf c drained
    if (t < 14) STAGE(Abase + kt2, lAc);         // Alo(t+2)
    WV(2);                                       // tile t+1 fully landed
    BAR();
    RD_ALO(lAn); RD_B0(lBn);
    MM(ahi, b1f, 4, 2);                          // overlaps tile-boundary reads
    RD_B1(lBn);
    if (t < 14) STAGE(Abase + 128 * DDIM + kt2, lAc + 8192);  // Ahi(t+2)
    u16* tp = lAc; lAc = lAn; lAn = tp;
    tp = lBc; lBc = lBn; lBn = tp;
  }
  // ---- final tile t=15: no stages, no barriers ----
  WL(4);
  MM(alo, b0f, 0, 0);
  RD_AHI(lAc);
  WL(8);
  MM(alo, b1f, 0, 2);
  WL(0);
  MM(ahi, b0f, 4, 0);
  MM(ahi, b1f, 4, 2);

#undef STAGE
#undef WL
#undef WV
#undef BAR

  // ---- epilogue: e = exp(logit), write (bf16 or f32), row-sums ----
  const int g = ks;                 // C/D: row = g*4 + j, col = lane&15
  float rsum[8][4];
  #pragma unroll
  for (int mi = 0; mi < 8; ++mi)
    #pragma unroll
    for (int j = 0; j < 4; ++j) rsum[mi][j] = 0.f;

  const size_t grow0 = (size_t)(bm * 256 + wm * 128);
  const int gcol0 = bn * 256 + wn * 64;
  #pragma unroll
  for (int mi = 0; mi < 8; ++mi) {
    const int rofs = (mi >> 2) * 64 + (mi & 3) * 16 + g * 4;
    #pragma unroll
    for (int j = 0; j < 4; ++j) {
      const size_t row = grow0 + rofs + j;
      #pragma unroll
      for (int ni = 0; ni < 4; ++ni) {
        const int col = gcol0 + (ni >> 1) * 32 + (ni & 1) * 16 + al;
        float e = __expf(acc[mi][ni >> 1][(ni & 1) * 2 + 0] * 0.f +  // placeholder avoided below
                         0.f);
        (void)e;
      }
    }
  }
  // (real epilogue below — the loop above was a miscompile guard; recompute cleanly)
  #pragma unroll
  for (int mi = 0; mi < 8; ++mi) {
    const int rofs = (mi >> 2) * 64 + (mi & 3) * 16 + g * 4;
    #pragma unroll
    for (int j = 0; j < 4; ++j) {
      const size_t row = grow0 + rofs + j;
      #pragma unroll
      for (int ni = 0; ni < 4; ++ni) {
        const int col = gcol0 + (ni >> 1) * 32 + (ni & 1) * 16 + al;
        float e = __expf(acc[mi][ni][j]);
        if (col == PAD_WORD) e = 0.f;
        rsum[mi][j] += e;
        if (use_bf16) ebf[row * VOCAB + col] = f2bf(e);
        else          out[row * VOCAB + col] = e;
      }
    }
  }
  #pragma unroll
  for (int mi = 0; mi < 8; ++mi)
    #pragma unroll
    for (int j = 0; j < 4; ++j) {
      float v = rsum[mi][j];
      v += __shfl_xor(v, 1);
      v += __shfl_xor(v, 2);
      v += __shfl_xor(v, 4);
      v += __shfl_xor(v, 8);
      rsum[mi][j] = v;
    }
  if (al == 0) {
    #pragma unroll
    for (int mi = 0; mi < 8; ++mi)
      #pragma unroll
      for (int j = 0; j < 4; ++j)
        rowacc[wn][wm * 128 + (mi >> 2) * 64 + (mi & 3) * 16 + g * 4 + j] =
            rsum[mi][j];
  }
  __syncthreads();
  if (tid < 256)
    partial[(size_t)bn * NROWS + bm * 256 + tid] =
        rowacc[0][tid] + rowacc[1][tid] + rowacc[2][tid] + rowacc[3][tid];
}

// ---------------- kernel 3: reduce partials -> scale/ofs ----------------
__global__ __launch_bounds__(256) void rowsum_kernel(
    const float* __restrict__ partial, const float* __restrict__ pcopy,
    float* __restrict__ scale, float* __restrict__ ofs)
{
  const int n = blockIdx.x * 256 + threadIdx.x;
  if (n >= NROWS) return;
  float s = 0.f;
  for (int j = 0; j < NBN2; ++j) s += partial[(size_t)j * NROWS + n];
  const float p = pcopy[n];
  scale[n] = (1.0f - p) / s;
  ofs[n]   = (1.0f - p) * 1e-20f;
}

// ---------------- kernel 4a: normalize from bf16 exp -> f32 out ----------------
__global__ __launch_bounds__(256) void norm_bf16_kernel(
    const u16* __restrict__ ebf, float* __restrict__ out,
    const float* __restrict__ scale, const float* __restrict__ ofs)
{
  const int total8 = NROWS * VOCAB / 8;     // VOCAB/8 = 4000
  const int stride = gridDim.x * blockDim.x;
  for (int i = blockIdx.x * 256 + threadIdx.x; i < total8; i += stride) {
    const int n = i / (VOCAB / 8);
    ushort4 v0 = ((const ushort4*)ebf)[i * 2];
    ushort4 v1 = ((const ushort4*)ebf)[i * 2 + 1];
    const float sc = scale[n], of = ofs[n];
    float4 o0, o1;
    o0.x = bf2f(v0.x) * sc + of; o0.y = bf2f(v0.y) * sc + of;
    o0.z = bf2f(v0.z) * sc + of; o0.w = bf2f(v0.w) * sc + of;
    o1.x = bf2f(v1.x) * sc + of; o1.y = bf2f(v1.y) * sc + of;
    o1.z = bf2f(v1.z) * sc + of; o1.w = bf2f(v1.w) * sc + of;
    ((float4*)out)[i * 2]     = o0;
    ((float4*)out)[i * 2 + 1] = o1;
  }
}

// ---------------- kernel 4b: normalize f32 in place (fallback) ----------------
__global__ __launch_bounds__(256) void norm_kernel(
    float* __restrict__ out, const float* __restrict__ scale,
    const float* __restrict__ ofs)
{
  const int total4 = NROWS * VOCAB / 4;
  const int stride = gridDim.x * blockDim.x;
  for (int i = blockIdx.x * 256 + threadIdx.x; i < total4; i += stride) {
    const int n = i / (VOCAB / 4);
    float4* p = (float4*)out + i;
    float4 v = *p;
    const float sc = scale[n], of = ofs[n];
    v.x = v.x * sc + of;
    v.y = v.y * sc + of;
    v.z = v.z * sc + of;
    v.w = v.w * sc + of;
    *p = v;
  }
}

// ---------------- kernel 5: scatter-add copy mass ----------------
__global__ __launch_bounds__(256) void scatter_kernel(
    float* __restrict__ out, const float* __restrict__ attn,
    const int* __restrict__ src, const float* __restrict__ pcopy)
{
  const int t = blockIdx.x * 256 + threadIdx.x;   // 65536 total
  const int n = t >> 6;
  const int s = t & 63;
  const int b = n & (BATCH - 1);
  const int v = src[s * BATCH + b];
  const float w = pcopy[n] * attn[(size_t)n * SLEN + s];
  atomicAdd(out + (size_t)n * VOCAB + v, w);
}

extern "C" void kernel_launch(void* const* d_in, const int* in_sizes, int n_in,
                              void* d_out, int out_size, void* d_ws, size_t ws_size,
                              hipStream_t stream) {
  const float* hidden = (const float*)d_in[0];
  const float* attn   = (const float*)d_in[1];
  const int*   src    = (const int*)d_in[2];
  const float* W      = (const float*)d_in[3];
  const float* w_copy = (const float*)d_in[4];
  const float* b_copy = (const float*)d_in[5];
  float* out = (float*)d_out;

  char* ws = (char*)d_ws;
  u16*   Wb      = (u16*)ws;                                    // 65,536,000 B
  u16*   hbf     = (u16*)(ws + 65536000);                       //  2,097,152 B
  float* pcopy   = (float*)(ws + 67633152);                     //      4,096 B
  float* partial = (float*)(ws + 67637248);                     //  1,024,000 B
  float* scale   = (float*)(ws + 68661248);                     //      4,096 B
  float* ofs     = (float*)(ws + 68665344);                     //      4,096 B
  u16*   ebf     = (u16*)(ws + 68669440);                       // 65,536,000 B
  const size_t need_bf16 = 68669440ull + 65536000ull;
  const int use_bf16 = (ws_size >= need_bf16) ? 1 : 0;

  prep_convw_kernel<<<NROWS + 2048, 256, 0, stream>>>(
      hidden, w_copy, b_copy, hbf, pcopy, W, Wb);
  gemm_exp_kernel<<<4 * NBN2, 512, 0, stream>>>(hbf, Wb, out, ebf, partial, use_bf16);
  rowsum_kernel<<<(NROWS + 255) / 256, 256, 0, stream>>>(partial, pcopy, scale, ofs);
  if (use_bf16)
    norm_bf16_kernel<<<2048, 256, 0, stream>>>(ebf, out, scale, ofs);
  else
    norm_kernel<<<2048, 256, 0, stream>>>(out, scale, ofs);
  scatter_kernel<<<NROWS * SLEN / 256, 256, 0, stream>>>(out, attn, src, pcopy);
}

// Round 5
// 156.271 us; speedup vs baseline: 1.3823x; 1.0561x over previous
//
#include <hip/hip_runtime.h>
#include <stdint.h>

typedef unsigned short u16;
typedef unsigned int u32;

#define NROWS 1024
#define DDIM  1024
#define SLEN  64
#define BATCH 64
#define VOCAB 32000
#define NBN2  125            // 256-wide column blocks
#define PAD_WORD 1

typedef __attribute__((ext_vector_type(4))) float f32x4;
typedef __attribute__((ext_vector_type(8))) short s16x8;

__device__ __forceinline__ u16 f2bf(float x) {
  union { float f; u32 u; } v; v.f = x;
  u32 r = v.u + 0x7FFF + ((v.u >> 16) & 1);   // RNE
  return (u16)(r >> 16);
}
__device__ __forceinline__ float bf2f(u16 x) {
  union { u32 u; float f; } v; v.u = ((u32)x) << 16;
  return v.f;
}
// packed pair f32->bf16, round-half-up (bias ≤ 0.5 ulp, fine at our tolerance)
__device__ __forceinline__ u32 pkbf(float a, float b) {
  union { float f; u32 u; } va, vb; va.f = a; vb.f = b;
  return ((va.u + 0x8000u) >> 16) | ((vb.u + 0x8000u) & 0xFFFF0000u);
}

// ---------------- kernel 1: p_copy + hidden -> bf16 ----------------
__global__ __launch_bounds__(256) void prep_kernel(
    const float* __restrict__ hidden, const float* __restrict__ w_copy,
    const float* __restrict__ b_copy, u16* __restrict__ hbf,
    float* __restrict__ pcopy)
{
  const int n = blockIdx.x;
  const int tid = threadIdx.x;
  float4 h = ((const float4*)(hidden + (size_t)n * DDIM))[tid];
  float4 w = ((const float4*)w_copy)[tid];
  ushort4 hb;
  hb.x = f2bf(h.x); hb.y = f2bf(h.y); hb.z = f2bf(h.z); hb.w = f2bf(h.w);
  ((ushort4*)(hbf + (size_t)n * DDIM))[tid] = hb;
  float d = h.x * w.x + h.y * w.y + h.z * w.z + h.w * w.w;
  #pragma unroll
  for (int m = 1; m < 64; m <<= 1) d += __shfl_xor(d, m);
  __shared__ float ws4[4];
  if ((tid & 63) == 0) ws4[tid >> 6] = d;
  __syncthreads();
  if (tid == 0) {
    float s = ws4[0] + ws4[1] + ws4[2] + ws4[3] + b_copy[0];
    pcopy[n] = 1.0f / (1.0f + __expf(-s));
  }
}

// -------- kernel 2: 256x256 bf16 GEMM, B read as f32 W directly (reg-staged
//          + inline cvt), A via global_load_lds. 1 barrier / K-tile. exp epilogue. ----
__global__ __launch_bounds__(512, 2) void gemm_exp_kernel(
    const u16* __restrict__ A, const float* __restrict__ Wf,
    float* __restrict__ out, u16* __restrict__ ebf,
    float* __restrict__ partial, const int use_bf16)
{
  __shared__ u16 lA[2][16384];     // [dbuf][lo-half(8192) | hi-half]
  __shared__ u16 lB[2][16384];
  __shared__ float rowacc[4][256];

  const int tid  = threadIdx.x;
  const int lane = tid & 63;
  const int wid  = tid >> 6;        // 0..7
  const int wm   = wid >> 2;        // 0..1  (M)
  const int wn   = wid & 3;         // 0..3  (N)
  const int al   = lane & 15;
  const int ks   = lane >> 4;       // 0..3

  // bijective XCD-chunked swizzle for 500 blocks (q=62, r=4)
  const int orig = blockIdx.x;
  const int xcd  = orig & 7;
  const int idx  = orig >> 3;
  const int wg   = (xcd < 4 ? xcd * 63 : 252 + (xcd - 4) * 62) + idx;
  const int bm   = wg & 3;          // 4 M-blocks
  const int bn   = wg >> 2;         // 125 N-blocks

  const u16* Abase = A + (size_t)(bm * 256) * DDIM;

  // ---- A staging (global_load_lds, pre-swizzled source) ----
  const int s0  = wid * 128 + lane;      // 0..1023 (16B slots of a half-tile)
  const int rr0 = s0 >> 3;               // row within half (0..127)
  const int cs0 = (s0 & 7) ^ (rr0 & 7);  // pre-swizzled source slot

#define STAGEH(gptr, lptr) do { \
    __builtin_amdgcn_global_load_lds( \
        (const __attribute__((address_space(1))) u32*)((gptr) + (size_t)rr0 * DDIM + cs0 * 8), \
        (__attribute__((address_space(3))) u32*)((lptr) + s0 * 8), 16, 0, 0); \
    __builtin_amdgcn_global_load_lds( \
        (const __attribute__((address_space(1))) u32*)((gptr) + (size_t)(rr0 + 8) * DDIM + cs0 * 8), \
        (__attribute__((address_space(3))) u32*)((lptr) + s0 * 8 + 512), 16, 0, 0); \
  } while (0)
#define STAGE_A(lptr, kt) do { \
    STAGEH(Abase + (kt), (lptr)); \
    STAGEH(Abase + 128 * DDIM + (kt), (lptr) + 8192); \
  } while (0)

  // ---- B reg-staging: thread covers row (tid>>2) of each half, 16 f32 cols ----
  const int brow_st = tid >> 2;          // 0..127
  const int bk0     = (tid & 3) * 16;    // f32 col offset within 64-wide slab
  const float* Bsrc0 = Wf + (size_t)(bn * 256 + brow_st) * DDIM + bk0;
  const float* Bsrc1 = Bsrc0 + (size_t)128 * DDIM;
  f32x4 br[8];

#define ISSUE_B(kt) do { \
    br[0] = *(const f32x4*)(Bsrc0 + (kt));      \
    br[1] = *(const f32x4*)(Bsrc0 + (kt) + 4);  \
    br[2] = *(const f32x4*)(Bsrc0 + (kt) + 8);  \
    br[3] = *(const f32x4*)(Bsrc0 + (kt) + 12); \
    br[4] = *(const f32x4*)(Bsrc1 + (kt));      \
    br[5] = *(const f32x4*)(Bsrc1 + (kt) + 4);  \
    br[6] = *(const f32x4*)(Bsrc1 + (kt) + 8);  \
    br[7] = *(const f32x4*)(Bsrc1 + (kt) + 12); \
  } while (0)

  union pk8 { u32 w[4]; s16x8 v; };
#define CVT_WRITE_B(dstbase) do { \
    _Pragma("unroll") \
    for (int h_ = 0; h_ < 2; ++h_) { \
      _Pragma("unroll") \
      for (int j_ = 0; j_ < 2; ++j_) { \
        pk8 p_; \
        f32x4 f0_ = br[h_ * 4 + j_ * 2], f1_ = br[h_ * 4 + j_ * 2 + 1]; \
        p_.w[0] = pkbf(f0_.x, f0_.y); p_.w[1] = pkbf(f0_.z, f0_.w); \
        p_.w[2] = pkbf(f1_.x, f1_.y); p_.w[3] = pkbf(f1_.z, f1_.w); \
        const int sl_ = (((tid & 3) * 2 + j_) ^ (brow_st & 7)); \
        *(s16x8*)((dstbase) + h_ * 8192 + brow_st * 64 + sl_ * 8) = p_.v; \
      } \
    } \
  } while (0)

#define WL(n) do { asm volatile("s_waitcnt lgkmcnt(" #n ")" ::: "memory"); \
                   __builtin_amdgcn_sched_barrier(0); } while (0)
#define WV(n) do { asm volatile("s_waitcnt vmcnt(" #n ")" ::: "memory"); \
                   __builtin_amdgcn_sched_barrier(0); } while (0)
#define BAR() do { __builtin_amdgcn_sched_barrier(0); \
                   __builtin_amdgcn_s_barrier(); \
                   __builtin_amdgcn_sched_barrier(0); } while (0)

#define RD_ALO(buf) do { \
    _Pragma("unroll") \
    for (int mi = 0; mi < 4; ++mi) { \
      const u16* p_ = (buf) + wm * 8192 + (mi * 16 + al) * 64; \
      alo[mi][0] = *(const s16x8*)(p_ + (ks ^ (al & 7)) * 8); \
      alo[mi][1] = *(const s16x8*)(p_ + ((4 + ks) ^ (al & 7)) * 8); \
    } } while (0)
#define RD_AHI(buf) do { \
    _Pragma("unroll") \
    for (int mi = 0; mi < 4; ++mi) { \
      const u16* p_ = (buf) + wm * 8192 + (64 + mi * 16 + al) * 64; \
      ahi[mi][0] = *(const s16x8*)(p_ + (ks ^ (al & 7)) * 8); \
      ahi[mi][1] = *(const s16x8*)(p_ + ((4 + ks) ^ (al & 7)) * 8); \
    } } while (0)
#define RD_B0(buf) do { \
    _Pragma("unroll") \
    for (int ni = 0; ni < 2; ++ni) { \
      const u16* p_ = (buf) + (wn >> 1) * 8192 + ((wn & 1) * 64 + ni * 16 + al) * 64; \
      b0f[ni][0] = *(const s16x8*)(p_ + (ks ^ (al & 7)) * 8); \
      b0f[ni][1] = *(const s16x8*)(p_ + ((4 + ks) ^ (al & 7)) * 8); \
    } } while (0)
#define RD_B1(buf) do { \
    _Pragma("unroll") \
    for (int ni = 0; ni < 2; ++ni) { \
      const u16* p_ = (buf) + (wn >> 1) * 8192 + ((wn & 1) * 64 + 32 + ni * 16 + al) * 64; \
      b1f[ni][0] = *(const s16x8*)(p_ + (ks ^ (al & 7)) * 8); \
      b1f[ni][1] = *(const s16x8*)(p_ + ((4 + ks) ^ (al & 7)) * 8); \
    } } while (0)
#define MM(AF, BF, r0, c0) do { \
    __builtin_amdgcn_s_setprio(1); \
    _Pragma("unroll") \
    for (int mi = 0; mi < 4; ++mi) \
      _Pragma("unroll") \
      for (int ni = 0; ni < 2; ++ni) \
        _Pragma("unroll") \
        for (int kk = 0; kk < 2; ++kk) \
          acc[(r0) + mi][(c0) + ni] = __builtin_amdgcn_mfma_f32_16x16x32_bf16( \
              AF[mi][kk], BF[ni][kk], acc[(r0) + mi][(c0) + ni], 0, 0, 0); \
    __builtin_amdgcn_s_setprio(0); \
  } while (0)

  u16* lAc = &lA[0][0]; u16* lBc = &lB[0][0];
  u16* lAn = &lA[1][0]; u16* lBn = &lB[1][0];

  // ---- prologue ----
  ISSUE_B(0);                 // vm: 8
  STAGE_A(lAc, 0);            // vm: +4 = 12
  // hold Bload(1) issue until after cvt of tile0 (br regs single-buffered)
  WV(4);                      // Bload(0) retired (A may fly)
  CVT_WRITE_B(lBc);
  ISSUE_B(64);                // Bload(1), vm: A(≤4) + 8
  WV(8);                      // A(0) landed (Bload(1) remains)
  WL(0);                      // ds_writes drained
  BAR();

  f32x4 acc[8][4];
  #pragma unroll
  for (int i = 0; i < 8; ++i)
    #pragma unroll
    for (int j = 0; j < 4; ++j)
      acc[i][j] = (f32x4){0.f, 0.f, 0.f, 0.f};

  s16x8 alo[4][2], ahi[4][2], b0f[2][2], b1f[2][2];

  for (int t = 0; t < 15; ++t) {
    RD_ALO(lAc); RD_B0(lBc); RD_B1(lBc);   // 16 ds_reads
    WV(0);                                  // Bregs(t+1) landed
    CVT_WRITE_B(lBn);                       // 4 ds_writes into next buf
    STAGE_A(lAn, (t + 1) * 64);             // 4 gload_lds into next buf
    if (t < 14) ISSUE_B((t + 2) * 64);      // 8 dwordx4, depth-1 tile prefetch
    WL(8);                                  // alo+b0 retired (b1 + writes may fly)
    MM(alo, b0f, 0, 0);
    WL(4);                                  // b1 retired (writes may fly)
    MM(alo, b1f, 0, 2);
    RD_AHI(lAc);                            // 8 ds_reads
    WL(0);                                  // ahi ready, writes drained
    MM(ahi, b0f, 4, 0);
    if (t < 14) { WV(8); } else { WV(0); }  // A(t+1) landed (Bload(t+2) may fly)
    BAR();                                  // next buf fully ready for all waves
    MM(ahi, b1f, 4, 2);                     // reg-only, overlaps next-tile reads
    u16* tp = lAc; lAc = lAn; lAn = tp;
    tp = lBc; lBc = lBn; lBn = tp;
  }
  // ---- final tile t=15: reads + MFMA only ----
  RD_ALO(lAc); RD_B0(lBc); RD_B1(lBc);
  WL(4);
  MM(alo, b0f, 0, 0);
  RD_AHI(lAc);
  WL(8);
  MM(alo, b1f, 0, 2);
  WL(0);
  MM(ahi, b0f, 4, 0);
  MM(ahi, b1f, 4, 2);

#undef STAGEH
#undef STAGE_A
#undef ISSUE_B
#undef CVT_WRITE_B
#undef WL
#undef WV
#undef BAR

  // ---- epilogue: e = exp(logit), write (bf16 or f32), row-sums ----
  const int g = ks;                 // C/D: row = g*4 + j, col = lane&15
  float rsum[8][4];
  #pragma unroll
  for (int mi = 0; mi < 8; ++mi)
    #pragma unroll
    for (int j = 0; j < 4; ++j) rsum[mi][j] = 0.f;

  const size_t grow0 = (size_t)(bm * 256 + wm * 128);
  const int gcol0 = bn * 256 + wn * 64;
  #pragma unroll
  for (int mi = 0; mi < 8; ++mi) {
    const int rofs = (mi >> 2) * 64 + (mi & 3) * 16 + g * 4;
    #pragma unroll
    for (int j = 0; j < 4; ++j) {
      const size_t row = grow0 + rofs + j;
      #pragma unroll
      for (int ni = 0; ni < 4; ++ni) {
        const int col = gcol0 + (ni >> 1) * 32 + (ni & 1) * 16 + al;
        float e = __expf(acc[mi][ni][j]);
        if (col == PAD_WORD) e = 0.f;
        rsum[mi][j] += e;
        if (use_bf16) ebf[row * VOCAB + col] = f2bf(e);
        else          out[row * VOCAB + col] = e;
      }
    }
  }
  #pragma unroll
  for (int mi = 0; mi < 8; ++mi)
    #pragma unroll
    for (int j = 0; j < 4; ++j) {
      float v = rsum[mi][j];
      v += __shfl_xor(v, 1);
      v += __shfl_xor(v, 2);
      v += __shfl_xor(v, 4);
      v += __shfl_xor(v, 8);
      rsum[mi][j] = v;
    }
  if (al == 0) {
    #pragma unroll
    for (int mi = 0; mi < 8; ++mi)
      #pragma unroll
      for (int j = 0; j < 4; ++j)
        rowacc[wn][wm * 128 + (mi >> 2) * 64 + (mi & 3) * 16 + g * 4 + j] =
            rsum[mi][j];
  }
  __syncthreads();
  if (tid < 256)
    partial[(size_t)bn * NROWS + bm * 256 + tid] =
        rowacc[0][tid] + rowacc[1][tid] + rowacc[2][tid] + rowacc[3][tid];
}

// ---------------- kernel 3: reduce partials -> scale/ofs ----------------
__global__ __launch_bounds__(256) void rowsum_kernel(
    const float* __restrict__ partial, const float* __restrict__ pcopy,
    float* __restrict__ scale, float* __restrict__ ofs)
{
  const int n = blockIdx.x * 256 + threadIdx.x;
  if (n >= NROWS) return;
  float s = 0.f;
  for (int j = 0; j < NBN2; ++j) s += partial[(size_t)j * NROWS + n];
  const float p = pcopy[n];
  scale[n] = (1.0f - p) / s;
  ofs[n]   = (1.0f - p) * 1e-20f;
}

// ---------------- kernel 4a: normalize from bf16 exp -> f32 out ----------------
__global__ __launch_bounds__(256) void norm_bf16_kernel(
    const u16* __restrict__ ebf, float* __restrict__ out,
    const float* __restrict__ scale, const float* __restrict__ ofs)
{
  const int total8 = NROWS * VOCAB / 8;     // VOCAB/8 = 4000
  const int stride = gridDim.x * blockDim.x;
  for (int i = blockIdx.x * 256 + threadIdx.x; i < total8; i += stride) {
    const int n = i / (VOCAB / 8);
    ushort4 v0 = ((const ushort4*)ebf)[i * 2];
    ushort4 v1 = ((const ushort4*)ebf)[i * 2 + 1];
    const float sc = scale[n], of = ofs[n];
    float4 o0, o1;
    o0.x = bf2f(v0.x) * sc + of; o0.y = bf2f(v0.y) * sc + of;
    o0.z = bf2f(v0.z) * sc + of; o0.w = bf2f(v0.w) * sc + of;
    o1.x = bf2f(v1.x) * sc + of; o1.y = bf2f(v1.y) * sc + of;
    o1.z = bf2f(v1.z) * sc + of; o1.w = bf2f(v1.w) * sc + of;
    ((float4*)out)[i * 2]     = o0;
    ((float4*)out)[i * 2 + 1] = o1;
  }
}

// ---------------- kernel 4b: normalize f32 in place (fallback) ----------------
__global__ __launch_bounds__(256) void norm_kernel(
    float* __restrict__ out, const float* __restrict__ scale,
    const float* __restrict__ ofs)
{
  const int total4 = NROWS * VOCAB / 4;
  const int stride = gridDim.x * blockDim.x;
  for (int i = blockIdx.x * 256 + threadIdx.x; i < total4; i += stride) {
    const int n = i / (VOCAB / 4);
    float4* p = (float4*)out + i;
    float4 v = *p;
    const float sc = scale[n], of = ofs[n];
    v.x = v.x * sc + of;
    v.y = v.y * sc + of;
    v.z = v.z * sc + of;
    v.w = v.w * sc + of;
    *p = v;
  }
}

// ---------------- kernel 5: scatter-add copy mass ----------------
__global__ __launch_bounds__(256) void scatter_kernel(
    float* __restrict__ out, const float* __restrict__ attn,
    const int* __restrict__ src, const float* __restrict__ pcopy)
{
  const int t = blockIdx.x * 256 + threadIdx.x;   // 65536 total
  const int n = t >> 6;
  const int s = t & 63;
  const int b = n & (BATCH - 1);
  const int v = src[s * BATCH + b];
  const float w = pcopy[n] * attn[(size_t)n * SLEN + s];
  atomicAdd(out + (size_t)n * VOCAB + v, w);
}

extern "C" void kernel_launch(void* const* d_in, const int* in_sizes, int n_in,
                              void* d_out, int out_size, void* d_ws, size_t ws_size,
                              hipStream_t stream) {
  const float* hidden = (const float*)d_in[0];
  const float* attn   = (const float*)d_in[1];
  const int*   src    = (const int*)d_in[2];
  const float* W      = (const float*)d_in[3];
  const float* w_copy = (const float*)d_in[4];
  const float* b_copy = (const float*)d_in[5];
  float* out = (float*)d_out;

  char* ws = (char*)d_ws;
  u16*   hbf     = (u16*)ws;                                   //  2,097,152 B
  float* pcopy   = (float*)(ws + 2097152);                     //      4,096 B
  float* partial = (float*)(ws + 2101248);                     //  1,024,000 B
  float* scale   = (float*)(ws + 3125248);                     //      4,096 B
  float* ofs     = (float*)(ws + 3129344);                     //      4,096 B
  u16*   ebf     = (u16*)(ws + 3133440);                       // 65,536,000 B
  const size_t need_bf16 = 3133440ull + 65536000ull;
  const int use_bf16 = (ws_size >= need_bf16) ? 1 : 0;

  prep_kernel<<<NROWS, 256, 0, stream>>>(hidden, w_copy, b_copy, hbf, pcopy);
  gemm_exp_kernel<<<4 * NBN2, 512, 0, stream>>>(hbf, W, out, ebf, partial, use_bf16);
  rowsum_kernel<<<(NROWS + 255) / 256, 256, 0, stream>>>(partial, pcopy, scale, ofs);
  if (use_bf16)
    norm_bf16_kernel<<<2048, 256, 0, stream>>>(ebf, out, scale, ofs);
  else
    norm_kernel<<<2048, 256, 0, stream>>>(out, scale, ofs);
  scatter_kernel<<<NROWS * SLEN / 256, 256, 0, stream>>>(out, attn, src, pcopy);
}